// Round 1
// baseline (1592.484 us; speedup 1.0000x reference)
//
#include <hip/hip_runtime.h>
#include <math.h>

// ============================================================================
// MinimalNetwork: radial MLP (10->100->100->100 swish ->1216) feeding an
// e3nn tensor-product message + scatter-add.
// Pipeline per chunk of EC edges:
//   [once] c3_build + c3_norm : compute real Wigner-3j tables on device
//   radial_hidden : h2[k][EC] (k-major, fp32) in ws
//   gemm_w3       : Rt[col][EC] = h2^T @ (W3/10), col-major so TP reads coalesce
//   tp_kernel     : per-edge tensor product + atomicAdd scatter into d_out
// ============================================================================

#define FEATD 72
#define NCOL 1216
#define SWISH_SCALE 1.679177f

// ---- coupling-table metadata (lo,li,lf) combos, entry offsets into C3 ----
constexpr int NCOMBO = 19;
constexpr int CB_LO[NCOMBO] = {0,0,0,1,1,1,1,1,1,1,2,2,2,2,2,2,2,2,2};
constexpr int CB_LI[NCOMBO] = {0,1,2,0,1,1,1,2,2,2,0,1,1,1,2,2,2,2,2};
constexpr int CB_LF[NCOMBO] = {0,1,2,1,0,1,2,1,2,3,2,1,2,3,0,1,2,3,4};
constexpr int CB_OFF[NCOMBO] = {0,1,10,35,44,53,80,125,170,245,350,375,420,495,600,625,700,825,1000};
constexpr int CB_SZ[NCOMBO]  = {1,9,25,9,9,27,45,45,75,105,25,45,75,105,25,75,125,175,225};
constexpr int C3TOT = 1225;

// C3 storage offset by [lo][li][lf] (absolute lf index)
constexpr int C3OFFT[3][3][5] = {
  { {0,-1,-1,-1,-1}, {-1,1,-1,-1,-1}, {-1,-1,10,-1,-1} },
  { {-1,35,-1,-1,-1}, {44,53,80,-1,-1}, {-1,125,170,245,-1} },
  { {-1,-1,350,-1,-1}, {-1,375,420,495,-1}, {600,625,700,825,1000} }
};
// R column-block offsets by [lo][li]  (block = 8u*8v*nlf floats)
constexpr int ROFFT[3][3] = {{0,64,128},{192,256,448},{640,704,896}};
constexpr int FOFFT[3]   = {0,8,32};   // feature offsets per li
constexpr int OUTOFFT[3] = {0,8,32};   // output offsets per lo

__device__ const double d_fact[11] = {1.,1.,2.,6.,24.,120.,720.,5040.,40320.,362880.,3628800.};

// ---------------------------------------------------------------------------
// Wigner 3j (complex basis, Racah) in double precision
// ---------------------------------------------------------------------------
__device__ double w3j_entry(int j1,int j2,int j3,int m1,int m2,int m3){
  if (m1+m2+m3 != 0) return 0.0;
  int dj = j1-j2; if (dj<0) dj=-dj;
  if (j3 < dj || j3 > j1+j2) return 0.0;
  int t1 = j2 - m1 - j3, t2 = j1 + m2 - j3;
  int kmin = 0; if (t1>kmin) kmin=t1; if (t2>kmin) kmin=t2;
  int kmax = j1+j2-j3; if (j1-m1<kmax) kmax=j1-m1; if (j2+m2<kmax) kmax=j2+m2;
  double s = 0.0;
  for (int k=kmin;k<=kmax;++k){
    double den = d_fact[k]*d_fact[k-t1]*d_fact[k-t2]*d_fact[j1+j2-j3-k]
               * d_fact[j1-m1-k]*d_fact[j2+m2-k];
    s += ((k&1)? -1.0:1.0)/den;
  }
  double pref = sqrt(d_fact[j1+j2-j3]*d_fact[j1-j2+j3]*d_fact[-j1+j2+j3]/d_fact[j1+j2+j3+1]
               * d_fact[j1+m1]*d_fact[j1-m1]*d_fact[j2+m2]*d_fact[j2-m2]
               * d_fact[j3+m3]*d_fact[j3-m3]);
  int ex = j1-j2-m3;
  if (ex & 1) pref = -pref;
  return pref*s;
}

// complex->real change-of-basis entry U[row][col] for given l
__device__ void cob(int l, int r, int c, double& re, double& im){
  re = 0.0; im = 0.0;
  int mr = r - l, mc = c - l;
  const double s = 0.70710678118654752440;
  if (mr == 0) { if (mc == 0) re = 1.0; return; }
  if (mr > 0) {
    if (mc == mr)       re = (mr & 1) ? -s : s;
    else if (mc == -mr) re = s;
  } else {
    int m = -mr;
    if (mc == -m)      im = s;
    else if (mc == m)  im = (m & 1) ? s : -s;   // -i*(-1)^m*s
  }
}

// Each thread computes one (unnormalized) complex entry of one combo's tensor
__global__ void c3_build_kernel(double* __restrict__ Tre, double* __restrict__ Tim){
  int idx = blockIdx.x*64 + threadIdx.x;
  if (idx >= C3TOT) return;
  int c = 0;
  while (c+1 < NCOMBO && idx >= CB_OFF[c+1]) ++c;
  int lo = CB_LO[c], li = CB_LI[c], lf = CB_LF[c];
  int n2 = 2*li+1, n3 = 2*lf+1;
  int loc = idx - CB_OFF[c];
  int a = loc/(n2*n3), b = (loc/n3)%n2, g = loc%n3;
  double sre=0.0, sim=0.0;
  for (int m1=-lo; m1<=lo; ++m1){
    for (int m2=-li; m2<=li; ++m2){
      int m3 = -m1-m2;
      if (m3 < -lf || m3 > lf) continue;
      double w = w3j_entry(lo,li,lf,m1,m2,m3);
      if (w == 0.0) continue;
      double r1,i1,r2,i2,r3,i3;
      cob(lo, a, m1+lo, r1,i1);
      cob(li, b, m2+li, r2,i2);
      cob(lf, g, m3+lf, r3,i3);
      double rr = r1*r2 - i1*i2, ri = r1*i2 + i1*r2;
      double fr = rr*r3 - ri*i3, fi = rr*i3 + ri*r3;
      sre += fr*w; sim += fi*w;
    }
  }
  Tre[idx] = sre; Tim[idx] = sim;
}

// One wave per combo: pick real/imag part by Frobenius norm, normalize, cast f32
__global__ void c3_norm_kernel(const double* __restrict__ Tre, const double* __restrict__ Tim,
                               float* __restrict__ C3f){
  int c = blockIdx.x;
  int off = CB_OFF[c], sz = CB_SZ[c];
  int t = threadIdx.x;
  double sre=0.0, sim=0.0;
  for (int p=t; p<sz; p+=64){ double x=Tre[off+p], y=Tim[off+p]; sre+=x*x; sim+=y*y; }
  for (int m=1; m<64; m<<=1){ sre += __shfl_xor(sre, m, 64); sim += __shfl_xor(sim, m, 64); }
  bool useRe = (sre >= sim);
  double n = sqrt(useRe ? sre : sim);
  double inv = (n > 0.0) ? 1.0/n : 1.0;
  for (int p=t; p<sz; p+=64){
    double v = useRe ? Tre[off+p] : Tim[off+p];
    C3f[off+p] = (float)(v*inv);
  }
}

// ---------------------------------------------------------------------------
// Radial hidden chain: basis(10) -> 100 -> 100 -> 100 (swish each layer).
// Output h_ws is K-MAJOR: h_ws[k*EC + e] so the GEMM can stage A conflict-free.
// Block = 256 threads handles 64 edges.
// ---------------------------------------------------------------------------
__device__ __forceinline__ float swishf(float s){
  return SWISH_SCALE * s / (1.f + __expf(-s));
}

__global__ __launch_bounds__(256) void radial_hidden_kernel(
    const float* __restrict__ radii,
    const float* __restrict__ W0, const float* __restrict__ W1, const float* __restrict__ W2,
    float* __restrict__ h_ws, int e0, int EC, int E)
{
  __shared__ float sW[10000];
  __shared__ float sX[6400];   // [er][k], pitch 100
  __shared__ float sY[6400];
  __shared__ float sbas[640];
  const int t = threadIdx.x;
  const int et0 = blockIdx.x*64;

  for (int p=t; p<640; p+=256){
    int er = p/10, k = p%10;
    int eg = e0 + et0 + er;
    float r = (eg < E) ? radii[eg] : 0.f;
    float c = 0.7f + (2.5f/9.0f)*(float)k;
    float d = (r - c) * (9.0f/2.5f);
    sbas[p] = __expf(-d*d);
  }
  for (int p=t; p<1000; p+=256) sW[p] = W0[p]*0.3162277660168379f; // 1/sqrt(10)
  __syncthreads();
  // layer 1 (K=10)
  for (int p=t; p<6400; p+=256){
    int er = p/100, o = p%100;
    float s = 0.f;
    #pragma unroll
    for (int k=0;k<10;++k) s += sbas[er*10+k]*sW[k*100+o];
    sX[p] = swishf(s);
  }
  __syncthreads();
  for (int p=t; p<10000; p+=256) sW[p] = W1[p]*0.1f;
  __syncthreads();
  // layer 2 (K=100), 4x4 register tiles
  for (int q=t; q<400; q+=256){
    int erb = (q/25)*4, ob = (q%25)*4;
    float acc[4][4] = {};
    for (int k=0;k<100;++k){
      float4 w = *(const float4*)&sW[k*100+ob];
      #pragma unroll
      for (int i=0;i<4;++i){
        float a = sX[(erb+i)*100+k];
        acc[i][0]+=a*w.x; acc[i][1]+=a*w.y; acc[i][2]+=a*w.z; acc[i][3]+=a*w.w;
      }
    }
    #pragma unroll
    for (int i=0;i<4;++i){
      float4 v = make_float4(swishf(acc[i][0]),swishf(acc[i][1]),swishf(acc[i][2]),swishf(acc[i][3]));
      *(float4*)&sY[(erb+i)*100+ob] = v;
    }
  }
  __syncthreads();
  for (int p=t; p<10000; p+=256) sW[p] = W2[p]*0.1f;
  __syncthreads();
  // layer 3 (K=100) -> global, k-major
  for (int q=t; q<400; q+=256){
    int erb = (q/25)*4, ob = (q%25)*4;
    float acc[4][4] = {};
    for (int k=0;k<100;++k){
      float4 w = *(const float4*)&sW[k*100+ob];
      #pragma unroll
      for (int i=0;i<4;++i){
        float a = sY[(erb+i)*100+k];
        acc[i][0]+=a*w.x; acc[i][1]+=a*w.y; acc[i][2]+=a*w.z; acc[i][3]+=a*w.w;
      }
    }
    #pragma unroll
    for (int j=0;j<4;++j){
      float4 v = make_float4(swishf(acc[0][j]),swishf(acc[1][j]),swishf(acc[2][j]),swishf(acc[3][j]));
      *(float4*)&h_ws[(size_t)(ob+j)*EC + et0 + erb] = v;
    }
  }
}

// ---------------------------------------------------------------------------
// GEMM: Rt[col][e] = sum_k h_ws[k][e] * (W3[k][col] * 0.1)
// 128 edges x 128 cols per block, 8x8 per thread (split 64+64 for bank spread)
// ---------------------------------------------------------------------------
__global__ __launch_bounds__(256) void gemm_w3_kernel(
    const float* __restrict__ h_ws, const float* __restrict__ W3,
    float* __restrict__ Rt, int e0, int EC, int E)
{
  __shared__ float sA[100*128];  // [k][e]
  __shared__ float sB[100*128];  // [k][c]
  const int t = threadIdx.x;
  const int et0 = blockIdx.x*128;
  const int c0  = blockIdx.y*128;

  for (int p=t; p<12800; p+=256){
    int k = p/128, e = p%128;
    sA[p] = h_ws[(size_t)k*EC + et0 + e];
  }
  for (int p=t; p<12800; p+=256){
    int k = p/128, c = p%128;
    sB[p] = (c0 + c < NCOL) ? 0.1f*W3[(size_t)k*NCOL + c0 + c] : 0.f;
  }
  __syncthreads();

  const int tr = t >> 4;    // 0..15
  const int tc = t & 15;    // 0..15
  float acc[2][2][4][4] = {};
  for (int k=0;k<100;++k){
    float4 a0 = *(const float4*)&sA[k*128 + tr*4];
    float4 a1 = *(const float4*)&sA[k*128 + 64 + tr*4];
    float4 b0 = *(const float4*)&sB[k*128 + tc*4];
    float4 b1 = *(const float4*)&sB[k*128 + 64 + tc*4];
    float av[2][4] = {{a0.x,a0.y,a0.z,a0.w},{a1.x,a1.y,a1.z,a1.w}};
    float bv[2][4] = {{b0.x,b0.y,b0.z,b0.w},{b1.x,b1.y,b1.z,b1.w}};
    #pragma unroll
    for (int eg=0; eg<2; ++eg)
      #pragma unroll
      for (int cg=0; cg<2; ++cg)
        #pragma unroll
        for (int i=0;i<4;++i)
          #pragma unroll
          for (int j=0;j<4;++j)
            acc[eg][cg][i][j] += av[eg][i]*bv[cg][j];
  }
  #pragma unroll
  for (int cg=0; cg<2; ++cg)
    #pragma unroll
    for (int j=0;j<4;++j){
      int col = c0 + cg*64 + tc*4 + j;
      if (col < NCOL){
        #pragma unroll
        for (int eg=0; eg<2; ++eg){
          float4 v = make_float4(acc[eg][cg][0][j],acc[eg][cg][1][j],acc[eg][cg][2][j],acc[eg][cg][3][j]);
          *(float4*)&Rt[(size_t)col*EC + et0 + eg*64 + tr*4] = v;
        }
      }
    }
}

// ---------------------------------------------------------------------------
// Tensor product + scatter. One lane = one edge; Rt reads coalesce across lanes.
// ---------------------------------------------------------------------------
template<int LO, int LI>
__device__ __forceinline__ void tp_pair(
    const float* __restrict__ Fsrc, const float* __restrict__ rshE,
    const float* __restrict__ Rt, int ECp, int el,
    const float* __restrict__ sC3, float (&acc)[8][2*LO+1])
{
  constexpr int NO = 2*LO+1, NI = 2*LI+1;
  constexpr int LMIN  = LO < LI ? LO : LI;
  constexpr int LFMIN = LO > LI ? LO-LI : LI-LO;
  constexpr int NLF = 2*LMIN+1;

  float Fb[8][NI];
  #pragma unroll
  for (int v=0; v<8; ++v)
    #pragma unroll
    for (int mi=0; mi<NI; ++mi)
      Fb[v][mi] = Fsrc[FOFFT[LI] + v*NI + mi];

  #pragma unroll
  for (int fi=0; fi<NLF; ++fi){
    const int lf = LFMIN + fi;
    const int nf = 2*lf+1;
    float y[9];
    #pragma unroll
    for (int mf=0; mf<9; ++mf) y[mf] = (mf < nf) ? rshE[lf*lf + mf] : 0.f;
    const float* C = sC3 + C3OFFT[LO][LI][lf];

    float tmp[8][NO];
    #pragma unroll
    for (int v=0;v<8;++v)
      #pragma unroll
      for (int o=0;o<NO;++o) tmp[v][o]=0.f;

    #pragma unroll
    for (int o=0;o<NO;++o)
      #pragma unroll
      for (int mi=0;mi<NI;++mi){
        float kv = 0.f;
        #pragma unroll
        for (int mf=0; mf<nf; ++mf) kv += C[(o*NI+mi)*nf+mf]*y[mf];
        #pragma unroll
        for (int v=0;v<8;++v) tmp[v][o] += kv*Fb[v][mi];
      }

    const float* rb = Rt + (size_t)(ROFFT[LO][LI] + fi)*ECp + el;
    #pragma unroll
    for (int u=0;u<8;++u)
      #pragma unroll
      for (int v=0;v<8;++v){
        float r = rb[(size_t)((u*8+v)*NLF)*ECp];
        #pragma unroll
        for (int o=0;o<NO;++o) acc[u][o] += r*tmp[v][o];
      }
  }
}

template<int LO>
__device__ __forceinline__ void tp_out(float* __restrict__ out, int tgt,
                                       const float (&acc)[8][2*LO+1], float nrm){
  constexpr int NO = 2*LO+1;
  float* dst = out + (size_t)tgt*FEATD + OUTOFFT[LO];
  #pragma unroll
  for (int u=0;u<8;++u)
    #pragma unroll
    for (int o=0;o<NO;++o)
      atomicAdd(&dst[u*NO+o], acc[u][o]*nrm);
}

__global__ __launch_bounds__(256) void tp_kernel(
    const float* __restrict__ feats, const int* __restrict__ ei,
    const float* __restrict__ rsh, const float* __restrict__ Rt,
    const float* __restrict__ C3g, float* __restrict__ out,
    int e0, int ECp, int E)
{
  __shared__ float sC3[1232];
  for (int p=threadIdx.x; p<C3TOT; p+=256) sC3[p] = C3g[p];
  __syncthreads();

  int el = blockIdx.x*256 + threadIdx.x;
  int e = e0 + el;
  if (e >= E) return;
  int src = ei[e], tgt = ei[E+e];
  const float* Fsrc = feats + (size_t)src*FEATD;
  const float* rshE = rsh + (size_t)e*25;

  {
    float acc[8][1] = {};
    tp_pair<0,0>(Fsrc, rshE, Rt, ECp, el, sC3, acc);
    tp_pair<0,1>(Fsrc, rshE, Rt, ECp, el, sC3, acc);
    tp_pair<0,2>(Fsrc, rshE, Rt, ECp, el, sC3, acc);
    tp_out<0>(out, tgt, acc, 0.72360125f);   // sqrt(pi/6)
  }
  {
    float acc[8][3] = {};
    tp_pair<1,0>(Fsrc, rshE, Rt, ECp, el, sC3, acc);
    tp_pair<1,1>(Fsrc, rshE, Rt, ECp, el, sC3, acc);
    tp_pair<1,2>(Fsrc, rshE, Rt, ECp, el, sC3, acc);
    tp_out<1>(out, tgt, acc, 0.8204867f);    // sqrt(3*pi/14)
  }
  {
    float acc[8][5] = {};
    tp_pair<2,0>(Fsrc, rshE, Rt, ECp, el, sC3, acc);
    tp_pair<2,1>(Fsrc, rshE, Rt, ECp, el, sC3, acc);
    tp_pair<2,2>(Fsrc, rshE, Rt, ECp, el, sC3, acc);
    tp_out<2>(out, tgt, acc, 0.9341652f);    // sqrt(5*pi/18)
  }
}

// ---------------------------------------------------------------------------
extern "C" void kernel_launch(void* const* d_in, const int* in_sizes, int n_in,
                              void* d_out, int out_size, void* d_ws, size_t ws_size,
                              hipStream_t stream)
{
  const float* feats = (const float*)d_in[0];
  const int*   ei    = (const int*)d_in[1];
  const float* radii = (const float*)d_in[2];
  const float* rsh   = (const float*)d_in[3];
  const float* W0    = (const float*)d_in[4];
  const float* W1    = (const float*)d_in[5];
  const float* W2    = (const float*)d_in[6];
  const float* W3    = (const float*)d_in[7];
  float* out = (float*)d_out;
  const int E = in_sizes[2];

  char* ws = (char*)d_ws;
  float*  C3f = (float*)ws;                    // 1225 f32
  double* Tre = (double*)(ws + 8192);          // 1225 f64
  double* Tim = (double*)(ws + 8192 + 12288);  // 1225 f64
  const size_t OFF_H = 32768;

  // chunk size: fit h (100*EC f32) + Rt (1216*EC f32) in ws; cap for L3 locality
  long long ecmax = (long long)((ws_size - OFF_H) / 5264);
  int EC = (int)((ecmax/256)*256);
  if (EC > 25600) EC = 25600;
  int ECeff = ((E + 255)/256)*256;
  if (EC > ECeff) EC = ECeff;
  if (EC < 256) EC = 256;

  float* h_ws = (float*)(ws + OFF_H);                      // [100][EC]
  float* Rt   = (float*)(ws + OFF_H + (size_t)EC*400);     // [1216][EC]

  hipMemsetAsync(d_out, 0, (size_t)out_size*sizeof(float), stream);
  c3_build_kernel<<<dim3((C3TOT+63)/64), dim3(64), 0, stream>>>(Tre, Tim);
  c3_norm_kernel<<<dim3(NCOMBO), dim3(64), 0, stream>>>(Tre, Tim, C3f);

  int nch = (E + EC - 1)/EC;
  for (int c=0; c<nch; ++c){
    int e0 = c*EC;
    radial_hidden_kernel<<<dim3(EC/64), dim3(256), 0, stream>>>(radii, W0, W1, W2, h_ws, e0, EC, E);
    gemm_w3_kernel<<<dim3(EC/128, (NCOL+127)/128), dim3(256), 0, stream>>>(h_ws, W3, Rt, e0, EC, E);
    tp_kernel<<<dim3(EC/256), dim3(256), 0, stream>>>(feats, ei, rsh, Rt, C3f, out, e0, EC, E);
  }
}

// Round 2
// 950.327 us; speedup vs baseline: 1.6757x; 1.6757x over previous
//
#include <hip/hip_runtime.h>
#include <hip/hip_bf16.h>
#include <math.h>

// ============================================================================
// MinimalNetwork: radial MLP (10->100->100->100 swish ->1216) feeding an
// e3nn tensor-product message + scatter-add.
// Round 2: bf16 MFMA GEMM for R = h @ (W3/10).
//   radial_hidden : h_bf[e][128] bf16 (k-contiguous, zero-padded 100..127)
//   prep_w3t      : W3t[1280][128] bf16 (transposed, 0.1-scaled, zero-padded)
//   gemm_mfma     : Rt[c][e] fp32 via mfma_f32_16x16x32_bf16; A=W3t rows (M=c),
//                   B=h rows (N=e) so C's col=lane&15 dim is the edge ->
//                   coalesced direct stores into col-major Rt (tp's layout)
//   tp_kernel     : per-edge tensor product + atomicAdd scatter (unchanged)
// ============================================================================

#define FEATD 72
#define NCOL 1216
#define SWISH_SCALE 1.679177f

typedef __attribute__((ext_vector_type(8))) short bf16x8;
typedef __attribute__((ext_vector_type(4))) float f32x4;

// ---- coupling-table metadata (lo,li,lf) combos, entry offsets into C3 ----
constexpr int NCOMBO = 19;
constexpr int CB_LO[NCOMBO] = {0,0,0,1,1,1,1,1,1,1,2,2,2,2,2,2,2,2,2};
constexpr int CB_LI[NCOMBO] = {0,1,2,0,1,1,1,2,2,2,0,1,1,1,2,2,2,2,2};
constexpr int CB_LF[NCOMBO] = {0,1,2,1,0,1,2,1,2,3,2,1,2,3,0,1,2,3,4};
constexpr int CB_OFF[NCOMBO] = {0,1,10,35,44,53,80,125,170,245,350,375,420,495,600,625,700,825,1000};
constexpr int CB_SZ[NCOMBO]  = {1,9,25,9,9,27,45,45,75,105,25,45,75,105,25,75,125,175,225};
constexpr int C3TOT = 1225;

constexpr int C3OFFT[3][3][5] = {
  { {0,-1,-1,-1,-1}, {-1,1,-1,-1,-1}, {-1,-1,10,-1,-1} },
  { {-1,35,-1,-1,-1}, {44,53,80,-1,-1}, {-1,125,170,245,-1} },
  { {-1,-1,350,-1,-1}, {-1,375,420,495,-1}, {600,625,700,825,1000} }
};
constexpr int ROFFT[3][3] = {{0,64,128},{192,256,448},{640,704,896}};
constexpr int FOFFT[3]   = {0,8,32};
constexpr int OUTOFFT[3] = {0,8,32};

__device__ const double d_fact[11] = {1.,1.,2.,6.,24.,120.,720.,5040.,40320.,362880.,3628800.};

// ---------------------------------------------------------------------------
// Wigner 3j (complex basis, Racah) in double precision
// ---------------------------------------------------------------------------
__device__ double w3j_entry(int j1,int j2,int j3,int m1,int m2,int m3){
  if (m1+m2+m3 != 0) return 0.0;
  int dj = j1-j2; if (dj<0) dj=-dj;
  if (j3 < dj || j3 > j1+j2) return 0.0;
  int t1 = j2 - m1 - j3, t2 = j1 + m2 - j3;
  int kmin = 0; if (t1>kmin) kmin=t1; if (t2>kmin) kmin=t2;
  int kmax = j1+j2-j3; if (j1-m1<kmax) kmax=j1-m1; if (j2+m2<kmax) kmax=j2+m2;
  double s = 0.0;
  for (int k=kmin;k<=kmax;++k){
    double den = d_fact[k]*d_fact[k-t1]*d_fact[k-t2]*d_fact[j1+j2-j3-k]
               * d_fact[j1-m1-k]*d_fact[j2+m2-k];
    s += ((k&1)? -1.0:1.0)/den;
  }
  double pref = sqrt(d_fact[j1+j2-j3]*d_fact[j1-j2+j3]*d_fact[-j1+j2+j3]/d_fact[j1+j2+j3+1]
               * d_fact[j1+m1]*d_fact[j1-m1]*d_fact[j2+m2]*d_fact[j2-m2]
               * d_fact[j3+m3]*d_fact[j3-m3]);
  int ex = j1-j2-m3;
  if (ex & 1) pref = -pref;
  return pref*s;
}

__device__ void cob(int l, int r, int c, double& re, double& im){
  re = 0.0; im = 0.0;
  int mr = r - l, mc = c - l;
  const double s = 0.70710678118654752440;
  if (mr == 0) { if (mc == 0) re = 1.0; return; }
  if (mr > 0) {
    if (mc == mr)       re = (mr & 1) ? -s : s;
    else if (mc == -mr) re = s;
  } else {
    int m = -mr;
    if (mc == -m)      im = s;
    else if (mc == m)  im = (m & 1) ? s : -s;
  }
}

__global__ void c3_build_kernel(double* __restrict__ Tre, double* __restrict__ Tim){
  int idx = blockIdx.x*64 + threadIdx.x;
  if (idx >= C3TOT) return;
  int c = 0;
  while (c+1 < NCOMBO && idx >= CB_OFF[c+1]) ++c;
  int lo = CB_LO[c], li = CB_LI[c], lf = CB_LF[c];
  int n2 = 2*li+1, n3 = 2*lf+1;
  int loc = idx - CB_OFF[c];
  int a = loc/(n2*n3), b = (loc/n3)%n2, g = loc%n3;
  double sre=0.0, sim=0.0;
  for (int m1=-lo; m1<=lo; ++m1){
    for (int m2=-li; m2<=li; ++m2){
      int m3 = -m1-m2;
      if (m3 < -lf || m3 > lf) continue;
      double w = w3j_entry(lo,li,lf,m1,m2,m3);
      if (w == 0.0) continue;
      double r1,i1,r2,i2,r3,i3;
      cob(lo, a, m1+lo, r1,i1);
      cob(li, b, m2+li, r2,i2);
      cob(lf, g, m3+lf, r3,i3);
      double rr = r1*r2 - i1*i2, ri = r1*i2 + i1*r2;
      double fr = rr*r3 - ri*i3, fi = rr*i3 + ri*r3;
      sre += fr*w; sim += fi*w;
    }
  }
  Tre[idx] = sre; Tim[idx] = sim;
}

__global__ void c3_norm_kernel(const double* __restrict__ Tre, const double* __restrict__ Tim,
                               float* __restrict__ C3f){
  int c = blockIdx.x;
  int off = CB_OFF[c], sz = CB_SZ[c];
  int t = threadIdx.x;
  double sre=0.0, sim=0.0;
  for (int p=t; p<sz; p+=64){ double x=Tre[off+p], y=Tim[off+p]; sre+=x*x; sim+=y*y; }
  for (int m=1; m<64; m<<=1){ sre += __shfl_xor(sre, m, 64); sim += __shfl_xor(sim, m, 64); }
  bool useRe = (sre >= sim);
  double n = sqrt(useRe ? sre : sim);
  double inv = (n > 0.0) ? 1.0/n : 1.0;
  for (int p=t; p<sz; p+=64){
    double v = useRe ? Tre[off+p] : Tim[off+p];
    C3f[off+p] = (float)(v*inv);
  }
}

// ---------------------------------------------------------------------------
// W3t[c][k] = bf16( 0.1 * W3[k][c] ), c in [0,1280), k in [0,128); zero-padded
// ---------------------------------------------------------------------------
__global__ __launch_bounds__(256) void prep_w3t_kernel(const float* __restrict__ W3,
                                                       __hip_bfloat16* __restrict__ W3t){
  int idx = blockIdx.x*256 + threadIdx.x;
  if (idx >= 1280*128) return;
  int c = idx >> 7, k = idx & 127;
  float v = (c < NCOL && k < 100) ? 0.1f*W3[(size_t)k*NCOL + c] : 0.f;
  W3t[idx] = __float2bfloat16(v);
}

// ---------------------------------------------------------------------------
// Radial hidden chain: basis(10) -> 100 -> 100 -> 100 (swish each layer).
// Output h_bf[e][128] bf16, k-contiguous, k=100..127 zeroed.
// ---------------------------------------------------------------------------
__device__ __forceinline__ float swishf(float s){
  return SWISH_SCALE * s / (1.f + __expf(-s));
}

__global__ __launch_bounds__(256) void radial_hidden_kernel(
    const float* __restrict__ radii,
    const float* __restrict__ W0, const float* __restrict__ W1, const float* __restrict__ W2,
    __hip_bfloat16* __restrict__ h_bf, int e0, int EC, int E)
{
  __shared__ float sW[10000];
  __shared__ float sX[6400];   // [er][k], pitch 100
  __shared__ float sY[6400];
  __shared__ float sbas[640];
  const int t = threadIdx.x;
  const int et0 = blockIdx.x*64;

  for (int p=t; p<640; p+=256){
    int er = p/10, k = p%10;
    int eg = e0 + et0 + er;
    float r = (eg < E) ? radii[eg] : 0.f;
    float c = 0.7f + (2.5f/9.0f)*(float)k;
    float d = (r - c) * (9.0f/2.5f);
    sbas[p] = __expf(-d*d);
  }
  for (int p=t; p<1000; p+=256) sW[p] = W0[p]*0.3162277660168379f; // 1/sqrt(10)
  __syncthreads();
  for (int p=t; p<6400; p+=256){
    int er = p/100, o = p%100;
    float s = 0.f;
    #pragma unroll
    for (int k=0;k<10;++k) s += sbas[er*10+k]*sW[k*100+o];
    sX[p] = swishf(s);
  }
  __syncthreads();
  for (int p=t; p<10000; p+=256) sW[p] = W1[p]*0.1f;
  __syncthreads();
  for (int q=t; q<400; q+=256){
    int erb = (q/25)*4, ob = (q%25)*4;
    float acc[4][4] = {};
    for (int k=0;k<100;++k){
      float4 w = *(const float4*)&sW[k*100+ob];
      #pragma unroll
      for (int i=0;i<4;++i){
        float a = sX[(erb+i)*100+k];
        acc[i][0]+=a*w.x; acc[i][1]+=a*w.y; acc[i][2]+=a*w.z; acc[i][3]+=a*w.w;
      }
    }
    #pragma unroll
    for (int i=0;i<4;++i){
      float4 v = make_float4(swishf(acc[i][0]),swishf(acc[i][1]),swishf(acc[i][2]),swishf(acc[i][3]));
      *(float4*)&sY[(erb+i)*100+ob] = v;
    }
  }
  __syncthreads();
  for (int p=t; p<10000; p+=256) sW[p] = W2[p]*0.1f;
  __syncthreads();
  // layer 3 -> global bf16, e-major rows of 128
  for (int q=t; q<400; q+=256){
    int erb = (q/25)*4, ob = (q%25)*4;
    float acc[4][4] = {};
    for (int k=0;k<100;++k){
      float4 w = *(const float4*)&sW[k*100+ob];
      #pragma unroll
      for (int i=0;i<4;++i){
        float a = sY[(erb+i)*100+k];
        acc[i][0]+=a*w.x; acc[i][1]+=a*w.y; acc[i][2]+=a*w.z; acc[i][3]+=a*w.w;
      }
    }
    #pragma unroll
    for (int i=0;i<4;++i){
      __hip_bfloat16 hv[4];
      #pragma unroll
      for (int j=0;j<4;++j) hv[j] = __float2bfloat16(swishf(acc[i][j]));
      *(short4*)&h_bf[(size_t)(et0+erb+i)*128 + ob] = *(short4*)hv;
    }
  }
  // zero the k=100..127 pad
  for (int p=t; p<64*28; p+=256){
    int er = p/28, k = 100 + p%28;
    h_bf[(size_t)(et0+er)*128 + k] = __float2bfloat16(0.f);
  }
}

// ---------------------------------------------------------------------------
// MFMA GEMM: Rt[c][e] = sum_k W3t[c][k] * h_bf[e][k]   (K=128, single pass)
// Block: 128 c x 128 e, 4 waves (2x2 of 64x64). LDS pitch 136 bf16 (2-way max).
// C frag: col(lane&15)=e (coalesced store), row(quad*4+reg)=c.
// ---------------------------------------------------------------------------
#define LP 136
__global__ __launch_bounds__(256) void gemm_mfma_kernel(
    const __hip_bfloat16* __restrict__ h_bf, const __hip_bfloat16* __restrict__ W3t,
    float* __restrict__ Rt, int EC)
{
  __shared__ __hip_bfloat16 sW[128*LP];
  __shared__ __hip_bfloat16 sH[128*LP];
  const int t = threadIdx.x;
  const int eb = blockIdx.x*128;
  const int cb = blockIdx.y*128;

  // stage 128 rows x 16 chunks of 8 bf16 (16B) each
  for (int p=t; p<2048; p+=256){
    int row = p>>4, kb = p&15;
    *(float4*)&sW[row*LP + kb*8] = *(const float4*)&W3t[(size_t)(cb+row)*128 + kb*8];
  }
  for (int p=t; p<2048; p+=256){
    int row = p>>4, kb = p&15;
    *(float4*)&sH[row*LP + kb*8] = *(const float4*)&h_bf[(size_t)(eb+row)*128 + kb*8];
  }
  __syncthreads();

  const int lane = t & 63;
  const int w    = t >> 6;
  const int wm   = (w & 1) * 64;   // c-half
  const int wn   = (w >> 1) * 64;  // e-half
  const int lr   = lane & 15;
  const int lq   = lane >> 4;

  f32x4 acc[4][4] = {};
  #pragma unroll
  for (int ks=0; ks<4; ++ks){
    bf16x8 a[4], b[4];
    #pragma unroll
    for (int mi=0; mi<4; ++mi)
      a[mi] = *(bf16x8*)&sW[(wm + mi*16 + lr)*LP + ks*32 + lq*8];
    #pragma unroll
    for (int ni=0; ni<4; ++ni)
      b[ni] = *(bf16x8*)&sH[(wn + ni*16 + lr)*LP + ks*32 + lq*8];
    #pragma unroll
    for (int mi=0; mi<4; ++mi)
      #pragma unroll
      for (int ni=0; ni<4; ++ni)
        acc[mi][ni] = __builtin_amdgcn_mfma_f32_16x16x32_bf16(a[mi], b[ni], acc[mi][ni], 0, 0, 0);
  }

  #pragma unroll
  for (int mi=0; mi<4; ++mi)
    #pragma unroll
    for (int ni=0; ni<4; ++ni){
      int e = eb + wn + ni*16 + lr;
      #pragma unroll
      for (int r=0; r<4; ++r){
        int c = cb + wm + mi*16 + lq*4 + r;
        if (c < NCOL) Rt[(size_t)c*EC + e] = acc[mi][ni][r];
      }
    }
}

// ---------------------------------------------------------------------------
// Tensor product + scatter. One lane = one edge; Rt reads coalesce across lanes.
// ---------------------------------------------------------------------------
template<int LO, int LI>
__device__ __forceinline__ void tp_pair(
    const float* __restrict__ Fsrc, const float* __restrict__ rshE,
    const float* __restrict__ Rt, int ECp, int el,
    const float* __restrict__ sC3, float (&acc)[8][2*LO+1])
{
  constexpr int NO = 2*LO+1, NI = 2*LI+1;
  constexpr int LMIN  = LO < LI ? LO : LI;
  constexpr int LFMIN = LO > LI ? LO-LI : LI-LO;
  constexpr int NLF = 2*LMIN+1;

  float Fb[8][NI];
  #pragma unroll
  for (int v=0; v<8; ++v)
    #pragma unroll
    for (int mi=0; mi<NI; ++mi)
      Fb[v][mi] = Fsrc[FOFFT[LI] + v*NI + mi];

  #pragma unroll
  for (int fi=0; fi<NLF; ++fi){
    const int lf = LFMIN + fi;
    const int nf = 2*lf+1;
    float y[9];
    #pragma unroll
    for (int mf=0; mf<9; ++mf) y[mf] = (mf < nf) ? rshE[lf*lf + mf] : 0.f;
    const float* C = sC3 + C3OFFT[LO][LI][lf];

    float tmp[8][NO];
    #pragma unroll
    for (int v=0;v<8;++v)
      #pragma unroll
      for (int o=0;o<NO;++o) tmp[v][o]=0.f;

    #pragma unroll
    for (int o=0;o<NO;++o)
      #pragma unroll
      for (int mi=0;mi<NI;++mi){
        float kv = 0.f;
        #pragma unroll
        for (int mf=0; mf<nf; ++mf) kv += C[(o*NI+mi)*nf+mf]*y[mf];
        #pragma unroll
        for (int v=0;v<8;++v) tmp[v][o] += kv*Fb[v][mi];
      }

    const float* rb = Rt + (size_t)(ROFFT[LO][LI] + fi)*ECp + el;
    #pragma unroll
    for (int u=0;u<8;++u)
      #pragma unroll
      for (int v=0;v<8;++v){
        float r = rb[(size_t)((u*8+v)*NLF)*ECp];
        #pragma unroll
        for (int o=0;o<NO;++o) acc[u][o] += r*tmp[v][o];
      }
  }
}

template<int LO>
__device__ __forceinline__ void tp_out(float* __restrict__ out, int tgt,
                                       const float (&acc)[8][2*LO+1], float nrm){
  constexpr int NO = 2*LO+1;
  float* dst = out + (size_t)tgt*FEATD + OUTOFFT[LO];
  #pragma unroll
  for (int u=0;u<8;++u)
    #pragma unroll
    for (int o=0;o<NO;++o)
      atomicAdd(&dst[u*NO+o], acc[u][o]*nrm);
}

__global__ __launch_bounds__(256) void tp_kernel(
    const float* __restrict__ feats, const int* __restrict__ ei,
    const float* __restrict__ rsh, const float* __restrict__ Rt,
    const float* __restrict__ C3g, float* __restrict__ out,
    int e0, int ECp, int E)
{
  __shared__ float sC3[1232];
  for (int p=threadIdx.x; p<C3TOT; p+=256) sC3[p] = C3g[p];
  __syncthreads();

  int el = blockIdx.x*256 + threadIdx.x;
  int e = e0 + el;
  if (e >= E) return;
  int src = ei[e], tgt = ei[E+e];
  const float* Fsrc = feats + (size_t)src*FEATD;
  const float* rshE = rsh + (size_t)e*25;

  {
    float acc[8][1] = {};
    tp_pair<0,0>(Fsrc, rshE, Rt, ECp, el, sC3, acc);
    tp_pair<0,1>(Fsrc, rshE, Rt, ECp, el, sC3, acc);
    tp_pair<0,2>(Fsrc, rshE, Rt, ECp, el, sC3, acc);
    tp_out<0>(out, tgt, acc, 0.72360125f);   // sqrt(pi/6)
  }
  {
    float acc[8][3] = {};
    tp_pair<1,0>(Fsrc, rshE, Rt, ECp, el, sC3, acc);
    tp_pair<1,1>(Fsrc, rshE, Rt, ECp, el, sC3, acc);
    tp_pair<1,2>(Fsrc, rshE, Rt, ECp, el, sC3, acc);
    tp_out<1>(out, tgt, acc, 0.8204867f);    // sqrt(3*pi/14)
  }
  {
    float acc[8][5] = {};
    tp_pair<2,0>(Fsrc, rshE, Rt, ECp, el, sC3, acc);
    tp_pair<2,1>(Fsrc, rshE, Rt, ECp, el, sC3, acc);
    tp_pair<2,2>(Fsrc, rshE, Rt, ECp, el, sC3, acc);
    tp_out<2>(out, tgt, acc, 0.9341652f);    // sqrt(5*pi/18)
  }
}

// ---------------------------------------------------------------------------
extern "C" void kernel_launch(void* const* d_in, const int* in_sizes, int n_in,
                              void* d_out, int out_size, void* d_ws, size_t ws_size,
                              hipStream_t stream)
{
  const float* feats = (const float*)d_in[0];
  const int*   ei    = (const int*)d_in[1];
  const float* radii = (const float*)d_in[2];
  const float* rsh   = (const float*)d_in[3];
  const float* W0    = (const float*)d_in[4];
  const float* W1    = (const float*)d_in[5];
  const float* W2    = (const float*)d_in[6];
  const float* W3    = (const float*)d_in[7];
  float* out = (float*)d_out;
  const int E = in_sizes[2];

  char* ws = (char*)d_ws;
  float*  C3f = (float*)ws;                    // 1225 f32
  double* Tre = (double*)(ws + 8192);          // 1225 f64
  double* Tim = (double*)(ws + 8192 + 12288);  // 1225 f64
  __hip_bfloat16* W3t = (__hip_bfloat16*)(ws + 32768);   // 1280*128 bf16 = 320KB
  const size_t OFF_H = 32768 + 327680;         // = 360448, 16B aligned

  // per-edge ws bytes: h_bf 256 + Rt(fp32) 4864 = 5120
  long long ecmax = (long long)((ws_size - OFF_H) / 5120);
  int ECeff = ((E + 255)/256)*256;
  int EC = (int)((ecmax/256)*256);
  if (EC > ECeff) EC = ECeff;
  if (EC < 256) EC = 256;

  __hip_bfloat16* h_bf = (__hip_bfloat16*)(ws + OFF_H);          // [EC][128]
  float* Rt = (float*)(ws + OFF_H + (size_t)EC*256);             // [1216][EC]

  hipMemsetAsync(d_out, 0, (size_t)out_size*sizeof(float), stream);
  c3_build_kernel<<<dim3((C3TOT+63)/64), dim3(64), 0, stream>>>(Tre, Tim);
  c3_norm_kernel<<<dim3(NCOMBO), dim3(64), 0, stream>>>(Tre, Tim, C3f);
  prep_w3t_kernel<<<dim3((1280*128+255)/256), dim3(256), 0, stream>>>(W3, W3t);

  int nch = (E + EC - 1)/EC;
  for (int c=0; c<nch; ++c){
    int e0 = c*EC;
    radial_hidden_kernel<<<dim3(EC/64), dim3(256), 0, stream>>>(radii, W0, W1, W2, h_bf, e0, EC, E);
    gemm_mfma_kernel<<<dim3(EC/128, 10), dim3(256), 0, stream>>>(h_bf, W3t, Rt, EC);
    tp_kernel<<<dim3(EC/256), dim3(256), 0, stream>>>(feats, ei, rsh, Rt, C3f, out, e0, EC, E);
  }
}

// Round 4
// 754.472 us; speedup vs baseline: 2.1107x; 1.2596x over previous
//
#include <hip/hip_runtime.h>
#include <hip/hip_bf16.h>
#include <math.h>

// ============================================================================
// MinimalNetwork, round 4: fused GEMM+TP (round-3 structure, role-bug fixed:
// 4 threads/edge in consume+scatter; all LDS indices bounded by 64).
//   radial_hidden : h_bf[e][136] bf16 (k-contig, pad 100..135 = 0)
//   prep_w3t      : W3t[1216][136] bf16, CHUNK-MAJOR column permutation:
//                   column c' = chunk*64 + (u*8+v), chunk = one (lo,li,lf).
//   fused_kernel  : per 64-edge block, 19 phases of 64 R-columns each:
//                   stage W3 chunk -> coop kv=C3*y -> MFMA 64cx64e -> LDS ->
//                   4-role TP consume -> (end) quad-merge + atomic scatter.
//                   R never materializes in global memory.
// ============================================================================

#define FEATD 72
#define NCOL 1216
#define SWISH_SCALE 1.679177f

typedef __attribute__((ext_vector_type(8))) short bf16x8;
typedef __attribute__((ext_vector_type(4))) float f32x4;

// ---- 19 (lo,li,lf) chunks; CB_OFF = offsets into the C3 coefficient pool ----
constexpr int NCOMBO = 19;
constexpr int CB_LO[NCOMBO] = {0,0,0,1,1,1,1,1,1,1,2,2,2,2,2,2,2,2,2};
constexpr int CB_LI[NCOMBO] = {0,1,2,0,1,1,1,2,2,2,0,1,1,1,2,2,2,2,2};
constexpr int CB_LF[NCOMBO] = {0,1,2,1,0,1,2,1,2,3,2,1,2,3,0,1,2,3,4};
constexpr int CB_OFF[NCOMBO] = {0,1,10,35,44,53,80,125,170,245,350,375,420,495,600,625,700,825,1000};
constexpr int CB_SZ[NCOMBO]  = {1,9,25,9,9,27,45,45,75,105,25,45,75,105,25,75,125,175,225};
constexpr int C3TOT = 1225;

constexpr int C3OFFT[3][3][5] = {
  { {0,-1,-1,-1,-1}, {-1,1,-1,-1,-1}, {-1,-1,10,-1,-1} },
  { {-1,35,-1,-1,-1}, {44,53,80,-1,-1}, {-1,125,170,245,-1} },
  { {-1,-1,350,-1,-1}, {-1,375,420,495,-1}, {600,625,700,825,1000} }
};
constexpr int ROFFT[3][3] = {{0,64,128},{192,256,448},{640,704,896}};
constexpr int FOFFT[3]   = {0,8,32};

__device__ const double d_fact[11] = {1.,1.,2.,6.,24.,120.,720.,5040.,40320.,362880.,3628800.};

// ---------------------------------------------------------------------------
// Wigner 3j (complex basis, Racah) in double precision + real change of basis
// ---------------------------------------------------------------------------
__device__ double w3j_entry(int j1,int j2,int j3,int m1,int m2,int m3){
  if (m1+m2+m3 != 0) return 0.0;
  int dj = j1-j2; if (dj<0) dj=-dj;
  if (j3 < dj || j3 > j1+j2) return 0.0;
  int t1 = j2 - m1 - j3, t2 = j1 + m2 - j3;
  int kmin = 0; if (t1>kmin) kmin=t1; if (t2>kmin) kmin=t2;
  int kmax = j1+j2-j3; if (j1-m1<kmax) kmax=j1-m1; if (j2+m2<kmax) kmax=j2+m2;
  double s = 0.0;
  for (int k=kmin;k<=kmax;++k){
    double den = d_fact[k]*d_fact[k-t1]*d_fact[k-t2]*d_fact[j1+j2-j3-k]
               * d_fact[j1-m1-k]*d_fact[j2+m2-k];
    s += ((k&1)? -1.0:1.0)/den;
  }
  double pref = sqrt(d_fact[j1+j2-j3]*d_fact[j1-j2+j3]*d_fact[-j1+j2+j3]/d_fact[j1+j2+j3+1]
               * d_fact[j1+m1]*d_fact[j1-m1]*d_fact[j2+m2]*d_fact[j2-m2]
               * d_fact[j3+m3]*d_fact[j3-m3]);
  int ex = j1-j2-m3;
  if (ex & 1) pref = -pref;
  return pref*s;
}

__device__ void cob(int l, int r, int c, double& re, double& im){
  re = 0.0; im = 0.0;
  int mr = r - l, mc = c - l;
  const double s = 0.70710678118654752440;
  if (mr == 0) { if (mc == 0) re = 1.0; return; }
  if (mr > 0) {
    if (mc == mr)       re = (mr & 1) ? -s : s;
    else if (mc == -mr) re = s;
  } else {
    int m = -mr;
    if (mc == -m)      im = s;
    else if (mc == m)  im = (m & 1) ? s : -s;
  }
}

__global__ void c3_build_kernel(double* __restrict__ Tre, double* __restrict__ Tim){
  int idx = blockIdx.x*64 + threadIdx.x;
  if (idx >= C3TOT) return;
  int c = 0;
  while (c+1 < NCOMBO && idx >= CB_OFF[c+1]) ++c;
  int lo = CB_LO[c], li = CB_LI[c], lf = CB_LF[c];
  int n2 = 2*li+1, n3 = 2*lf+1;
  int loc = idx - CB_OFF[c];
  int a = loc/(n2*n3), b = (loc/n3)%n2, g = loc%n3;
  double sre=0.0, sim=0.0;
  for (int m1=-lo; m1<=lo; ++m1){
    for (int m2=-li; m2<=li; ++m2){
      int m3 = -m1-m2;
      if (m3 < -lf || m3 > lf) continue;
      double w = w3j_entry(lo,li,lf,m1,m2,m3);
      if (w == 0.0) continue;
      double r1,i1,r2,i2,r3,i3;
      cob(lo, a, m1+lo, r1,i1);
      cob(li, b, m2+li, r2,i2);
      cob(lf, g, m3+lf, r3,i3);
      double rr = r1*r2 - i1*i2, ri = r1*i2 + i1*r2;
      double fr = rr*r3 - ri*i3, fi = rr*i3 + ri*r3;
      sre += fr*w; sim += fi*w;
    }
  }
  Tre[idx] = sre; Tim[idx] = sim;
}

__global__ void c3_norm_kernel(const double* __restrict__ Tre, const double* __restrict__ Tim,
                               float* __restrict__ C3f){
  int c = blockIdx.x;
  int off = CB_OFF[c], sz = CB_SZ[c];
  int t = threadIdx.x;
  double sre=0.0, sim=0.0;
  for (int p=t; p<sz; p+=64){ double x=Tre[off+p], y=Tim[off+p]; sre+=x*x; sim+=y*y; }
  for (int m=1; m<64; m<<=1){ sre += __shfl_xor(sre, m, 64); sim += __shfl_xor(sim, m, 64); }
  bool useRe = (sre >= sim);
  double n = sqrt(useRe ? sre : sim);
  double inv = (n > 0.0) ? 1.0/n : 1.0;
  for (int p=t; p<sz; p+=64){
    double v = useRe ? Tre[off+p] : Tim[off+p];
    C3f[off+p] = (float)(v*inv);
  }
}

// ---------------------------------------------------------------------------
// W3t[c'][k], c' chunk-major: c' = chunk*64 + uv maps to original column
// ROFFT[lo][li] + uv*nlf + fi. 0.1 scale folded. Pitch 136, pad k>=100 = 0.
// ---------------------------------------------------------------------------
__global__ __launch_bounds__(256) void prep_w3t_kernel(const float* __restrict__ W3,
                                                       __hip_bfloat16* __restrict__ W3t){
  int idx = blockIdx.x*256 + threadIdx.x;
  if (idx >= 1216*136) return;
  int cp = idx/136, k = idx%136;
  int chunk = cp>>6, uv = cp&63;
  int lo = CB_LO[chunk], li = CB_LI[chunk], lf = CB_LF[chunk];
  int lmin = lo<li ? lo : li;
  int nlf = 2*lmin+1;
  int fi = lf - (lo>li ? lo-li : li-lo);
  int c = ROFFT[lo][li] + uv*nlf + fi;
  float v = (k < 100) ? 0.1f*W3[(size_t)k*NCOL + c] : 0.f;
  W3t[idx] = __float2bfloat16(v);
}

// ---------------------------------------------------------------------------
// Radial hidden chain -> h_bf[e][136] bf16 (pad zeroed)
// ---------------------------------------------------------------------------
__device__ __forceinline__ float swishf(float s){
  return SWISH_SCALE * s / (1.f + __expf(-s));
}

__global__ __launch_bounds__(256) void radial_hidden_kernel(
    const float* __restrict__ radii,
    const float* __restrict__ W0, const float* __restrict__ W1, const float* __restrict__ W2,
    __hip_bfloat16* __restrict__ h_bf, int E)
{
  __shared__ float sW[10000];
  __shared__ float sX[6400];   // [er][k], pitch 100
  __shared__ float sY[6400];
  __shared__ float sbas[640];
  const int t = threadIdx.x;
  const int et0 = blockIdx.x*64;

  for (int p=t; p<640; p+=256){
    int er = p/10, k = p%10;
    int eg = et0 + er;
    float r = (eg < E) ? radii[eg] : 0.f;
    float c = 0.7f + (2.5f/9.0f)*(float)k;
    float d = (r - c) * (9.0f/2.5f);
    sbas[p] = __expf(-d*d);
  }
  for (int p=t; p<1000; p+=256) sW[p] = W0[p]*0.3162277660168379f; // 1/sqrt(10)
  __syncthreads();
  for (int p=t; p<6400; p+=256){
    int er = p/100, o = p%100;
    float s = 0.f;
    #pragma unroll
    for (int k=0;k<10;++k) s += sbas[er*10+k]*sW[k*100+o];
    sX[p] = swishf(s);
  }
  __syncthreads();
  for (int p=t; p<10000; p+=256) sW[p] = W1[p]*0.1f;
  __syncthreads();
  for (int q=t; q<400; q+=256){
    int erb = (q/25)*4, ob = (q%25)*4;
    float acc[4][4] = {};
    for (int k=0;k<100;++k){
      float4 w = *(const float4*)&sW[k*100+ob];
      #pragma unroll
      for (int i=0;i<4;++i){
        float a = sX[(erb+i)*100+k];
        acc[i][0]+=a*w.x; acc[i][1]+=a*w.y; acc[i][2]+=a*w.z; acc[i][3]+=a*w.w;
      }
    }
    #pragma unroll
    for (int i=0;i<4;++i){
      float4 v = make_float4(swishf(acc[i][0]),swishf(acc[i][1]),swishf(acc[i][2]),swishf(acc[i][3]));
      *(float4*)&sY[(erb+i)*100+ob] = v;
    }
  }
  __syncthreads();
  for (int p=t; p<10000; p+=256) sW[p] = W2[p]*0.1f;
  __syncthreads();
  for (int q=t; q<400; q+=256){
    int erb = (q/25)*4, ob = (q%25)*4;
    float acc[4][4] = {};
    for (int k=0;k<100;++k){
      float4 w = *(const float4*)&sW[k*100+ob];
      #pragma unroll
      for (int i=0;i<4;++i){
        float a = sY[(erb+i)*100+k];
        acc[i][0]+=a*w.x; acc[i][1]+=a*w.y; acc[i][2]+=a*w.z; acc[i][3]+=a*w.w;
      }
    }
    #pragma unroll
    for (int i=0;i<4;++i){
      __hip_bfloat16 hv[4];
      #pragma unroll
      for (int j=0;j<4;++j) hv[j] = __float2bfloat16(swishf(acc[i][j]));
      *(short4*)&h_bf[(size_t)(et0+erb+i)*136 + ob] = *(short4*)hv;
    }
  }
  // zero the k=100..135 pad
  for (int p=t; p<64*36; p+=256){
    int er = p/36, k = 100 + p%36;
    h_bf[(size_t)(et0+er)*136 + k] = __float2bfloat16(0.f);
  }
}

// ---------------------------------------------------------------------------
// Fused GEMM+TP. 256 threads = 4 waves; 64 edges/block; 4 roles/edge.
// ---------------------------------------------------------------------------
template<int LO,int LI,int LF>
__device__ __forceinline__ void phase(
    int chunk, const __hip_bfloat16* __restrict__ W3t,
    __hip_bfloat16* sH, __hip_bfloat16* sW3, float* sRt,
    __hip_bfloat16* sF, float* sRsh, float* sKV, const float* sC3,
    float (&acc)[8][9], int t)
{
  constexpr int NO = 2*LO+1, NI = 2*LI+1, NF = 2*LF+1;
  constexpr int C3B = C3OFFT[LO][LI][LF];
  constexpr int FO  = FOFFT[LI];
  constexpr int AO  = (LO==0) ? 0 : (LO==1) ? 1 : 4;

  __syncthreads();   // [A] prev phase's consume done (sKV/sRt/sW3 free)

  // ---- stage this chunk's 64 W3t rows (17408 B) ----
  {
    const float4* g = (const float4*)(W3t + (size_t)chunk*64*136);
    float4* s = (float4*)sW3;
    for (int p=t; p<1088; p+=256) s[p] = g[p];
  }
  // ---- cooperative kv[e][o*NI+mi] = sum_mf C3 * y ----
  {
    const int le = t & 63, wv = t >> 6;
    float y[NF];
    #pragma unroll
    for (int mf=0; mf<NF; ++mf) y[mf] = sRsh[le*26 + LF*LF + mf];
    for (int it = wv; it < NO*NI; it += 4){
      float s = 0.f;
      #pragma unroll
      for (int mf=0; mf<NF; ++mf) s += sC3[C3B + it*NF + mf] * y[mf];
      sKV[le*26 + it] = s;
    }
  }
  __syncthreads();   // [B] sW3 + sKV visible

  // ---- MFMA: Rt_chunk[c=uv][e], 64x64, K=128; each wave does 16 edges ----
  {
    const int lane = t & 63, wv = t >> 6;
    const int lr = lane & 15, lq = lane >> 4;
    f32x4 a4[4] = {};
    #pragma unroll
    for (int ks=0; ks<4; ++ks){
      bf16x8 b = *(const bf16x8*)&sH[(wv*16+lr)*136 + ks*32 + lq*8];
      #pragma unroll
      for (int ct=0; ct<4; ++ct){
        bf16x8 a = *(const bf16x8*)&sW3[(ct*16+lr)*136 + ks*32 + lq*8];
        a4[ct] = __builtin_amdgcn_mfma_f32_16x16x32_bf16(a, b, a4[ct], 0, 0, 0);
      }
    }
    #pragma unroll
    for (int ct=0; ct<4; ++ct)
      #pragma unroll
      for (int r=0; r<4; ++r)
        sRt[(ct*16 + lq*4 + r)*66 + wv*16 + lr] = a4[ct][r];
  }
  __syncthreads();   // [C] sRt visible

  // ---- TP consume: 4 roles/edge, role handles v in {2*role, 2*role+1} ----
  {
    const int e = t >> 2, role = t & 3;
    float Fv[2][NI];
    #pragma unroll
    for (int vv=0; vv<2; ++vv)
      #pragma unroll
      for (int mi=0; mi<NI; ++mi)
        Fv[vv][mi] = __bfloat162float(sF[e*74 + FO + (role*2+vv)*NI + mi]);
    float tmp[2][NO];
    #pragma unroll
    for (int vv=0; vv<2; ++vv)
      #pragma unroll
      for (int o=0; o<NO; ++o) tmp[vv][o] = 0.f;
    #pragma unroll
    for (int o=0; o<NO; ++o)
      #pragma unroll
      for (int mi=0; mi<NI; ++mi){
        float kvv = sKV[e*26 + o*NI + mi];
        #pragma unroll
        for (int vv=0; vv<2; ++vv) tmp[vv][o] += kvv * Fv[vv][mi];
      }
    #pragma unroll
    for (int u=0; u<8; ++u)
      #pragma unroll
      for (int vv=0; vv<2; ++vv){
        float r = sRt[(u*8 + role*2 + vv)*66 + e];
        #pragma unroll
        for (int o=0; o<NO; ++o) acc[u][AO+o] += r * tmp[vv][o];
      }
  }
}

__global__ __launch_bounds__(256,2) void fused_kernel(
    const float* __restrict__ feats, const int* __restrict__ ei,
    const float* __restrict__ rsh, const __hip_bfloat16* __restrict__ h_bf,
    const __hip_bfloat16* __restrict__ W3t, const float* __restrict__ C3g,
    float* __restrict__ out, int E)
{
  __shared__ __align__(16) __hip_bfloat16 sH[64*136];
  __shared__ __align__(16) __hip_bfloat16 sW3[64*136];
  __shared__ float sRt[64*66];
  __shared__ __hip_bfloat16 sF[64*74];
  __shared__ float sRsh[64*26];
  __shared__ float sKV[64*26];
  __shared__ float sC3[1228];
  __shared__ int sSrc[64], sTgt[64];

  const int t = threadIdx.x;
  const int eb = blockIdx.x*64;

  // ---- prologue staging ----
  {
    const float4* g = (const float4*)(h_bf + (size_t)eb*136);
    float4* s = (float4*)sH;
    for (int p=t; p<1088; p+=256) s[p] = g[p];
  }
  for (int p=t; p<64; p+=256){
    int e = eb + p;
    sSrc[p] = (e < E) ? ei[e]   : 0;
    sTgt[p] = (e < E) ? ei[E+e] : 0;
  }
  for (int p=t; p<1600; p+=256){
    int el = p/25, j = p%25;
    int e = eb + el;
    sRsh[el*26 + j] = (e < E) ? rsh[(size_t)e*25 + j] : 0.f;
  }
  for (int p=t; p<C3TOT; p+=256) sC3[p] = C3g[p];
  __syncthreads();
  for (int p=t; p<64*72; p+=256){
    int el = p/72, j = p%72;
    sF[el*74 + j] = __float2bfloat16(feats[(size_t)sSrc[el]*72 + j]);
  }

  float acc[8][9];
  #pragma unroll
  for (int u=0; u<8; ++u)
    #pragma unroll
    for (int j=0; j<9; ++j) acc[u][j] = 0.f;

  // ---- 19 phases (chunk order = CB tables) ----
  phase<0,0,0>( 0, W3t, sH, sW3, sRt, sF, sRsh, sKV, sC3, acc, t);
  phase<0,1,1>( 1, W3t, sH, sW3, sRt, sF, sRsh, sKV, sC3, acc, t);
  phase<0,2,2>( 2, W3t, sH, sW3, sRt, sF, sRsh, sKV, sC3, acc, t);
  phase<1,0,1>( 3, W3t, sH, sW3, sRt, sF, sRsh, sKV, sC3, acc, t);
  phase<1,1,0>( 4, W3t, sH, sW3, sRt, sF, sRsh, sKV, sC3, acc, t);
  phase<1,1,1>( 5, W3t, sH, sW3, sRt, sF, sRsh, sKV, sC3, acc, t);
  phase<1,1,2>( 6, W3t, sH, sW3, sRt, sF, sRsh, sKV, sC3, acc, t);
  phase<1,2,1>( 7, W3t, sH, sW3, sRt, sF, sRsh, sKV, sC3, acc, t);
  phase<1,2,2>( 8, W3t, sH, sW3, sRt, sF, sRsh, sKV, sC3, acc, t);
  phase<1,2,3>( 9, W3t, sH, sW3, sRt, sF, sRsh, sKV, sC3, acc, t);
  phase<2,0,2>(10, W3t, sH, sW3, sRt, sF, sRsh, sKV, sC3, acc, t);
  phase<2,1,1>(11, W3t, sH, sW3, sRt, sF, sRsh, sKV, sC3, acc, t);
  phase<2,1,2>(12, W3t, sH, sW3, sRt, sF, sRsh, sKV, sC3, acc, t);
  phase<2,1,3>(13, W3t, sH, sW3, sRt, sF, sRsh, sKV, sC3, acc, t);
  phase<2,2,0>(14, W3t, sH, sW3, sRt, sF, sRsh, sKV, sC3, acc, t);
  phase<2,2,1>(15, W3t, sH, sW3, sRt, sF, sRsh, sKV, sC3, acc, t);
  phase<2,2,2>(16, W3t, sH, sW3, sRt, sF, sRsh, sKV, sC3, acc, t);
  phase<2,2,3>(17, W3t, sH, sW3, sRt, sF, sRsh, sKV, sC3, acc, t);
  phase<2,2,4>(18, W3t, sH, sW3, sRt, sF, sRsh, sKV, sC3, acc, t);

  // ---- quad merge (lanes 4k..4k+3 share an edge) + atomic scatter ----
  #pragma unroll
  for (int u=0; u<8; ++u)
    #pragma unroll
    for (int j=0; j<9; ++j){
      acc[u][j] += __shfl_xor(acc[u][j], 1, 64);
      acc[u][j] += __shfl_xor(acc[u][j], 2, 64);
    }

  const int e = t >> 2, role = t & 3;
  const int eg = eb + e;
  if (eg < E){
    const int tgt = sTgt[e];
    float* dst = out + (size_t)tgt*FEATD;
    #pragma unroll
    for (int du=0; du<2; ++du){
      int u = role*2 + du;
      atomicAdd(&dst[u], acc[u][0]*0.72360125f);                 // lo=0: sqrt(pi/6)
      #pragma unroll
      for (int o=0; o<3; ++o)
        atomicAdd(&dst[8 + u*3 + o], acc[u][1+o]*0.8204867f);    // lo=1
      #pragma unroll
      for (int o=0; o<5; ++o)
        atomicAdd(&dst[32 + u*5 + o], acc[u][4+o]*0.9341652f);   // lo=2
    }
  }
}

// ---------------------------------------------------------------------------
extern "C" void kernel_launch(void* const* d_in, const int* in_sizes, int n_in,
                              void* d_out, int out_size, void* d_ws, size_t ws_size,
                              hipStream_t stream)
{
  const float* feats = (const float*)d_in[0];
  const int*   ei    = (const int*)d_in[1];
  const float* radii = (const float*)d_in[2];
  const float* rsh   = (const float*)d_in[3];
  const float* W0    = (const float*)d_in[4];
  const float* W1    = (const float*)d_in[5];
  const float* W2    = (const float*)d_in[6];
  const float* W3    = (const float*)d_in[7];
  float* out = (float*)d_out;
  const int E = in_sizes[2];

  const int EPAD   = ((E + 63)/64)*64;     // 100096
  const int NBLK   = EPAD/64;              // 1564

  char* ws = (char*)d_ws;
  float*  C3f = (float*)ws;                         // 1225 f32
  double* Tre = (double*)(ws + 8192);               // 1225 f64
  double* Tim = (double*)(ws + 20480);              // 1225 f64
  __hip_bfloat16* W3t  = (__hip_bfloat16*)(ws + 32768);   // 1216*136 bf16 = 330,752 B
  __hip_bfloat16* h_bf = (__hip_bfloat16*)(ws + 368640);  // EPAD*136 bf16

  hipMemsetAsync(d_out, 0, (size_t)out_size*sizeof(float), stream);
  c3_build_kernel<<<dim3((C3TOT+63)/64), dim3(64), 0, stream>>>(Tre, Tim);
  c3_norm_kernel<<<dim3(NCOMBO), dim3(64), 0, stream>>>(Tre, Tim, C3f);
  prep_w3t_kernel<<<dim3((1216*136+255)/256), dim3(256), 0, stream>>>(W3, W3t);
  radial_hidden_kernel<<<dim3(NBLK), dim3(256), 0, stream>>>(radii, W0, W1, W2, h_bf, E);
  fused_kernel<<<dim3(NBLK), dim3(256), 0, stream>>>(feats, ei, rsh, h_bf, W3t, C3f, out, E);
}

// Round 5
// 696.951 us; speedup vs baseline: 2.2849x; 1.0825x over previous
//
#include <hip/hip_runtime.h>
#include <hip/hip_bf16.h>
#include <math.h>

// ============================================================================
// MinimalNetwork, round 5: fused GEMM+TP writes dense per-edge messages
// (no atomics); CSR counting-sort + per-node gather does the scatter-add.
//   radial_hidden : h_bf[e][136] bf16 (k-contig, pad 100..135 = 0)
//   prep_w3t      : W3t[1216][136] bf16, chunk-major column permutation
//   fused_kernel  : 19 phases (stage W3 chunk -> kv=C3*y -> MFMA 64x64 ->
//                   LDS -> 4-role TP consume) -> quad-merge -> msg[e][72]
//   hist/scan/fill: CSR of edges by target node
//   gather_kernel : one wave per node, sums its message rows -> out (no memset)
// ============================================================================

#define FEATD 72
#define NCOL 1216
#define SWISH_SCALE 1.679177f

typedef __attribute__((ext_vector_type(8))) short bf16x8;
typedef __attribute__((ext_vector_type(4))) float f32x4;

// ---- 19 (lo,li,lf) chunks; CB_OFF = offsets into the C3 coefficient pool ----
constexpr int NCOMBO = 19;
constexpr int CB_LO[NCOMBO] = {0,0,0,1,1,1,1,1,1,1,2,2,2,2,2,2,2,2,2};
constexpr int CB_LI[NCOMBO] = {0,1,2,0,1,1,1,2,2,2,0,1,1,1,2,2,2,2,2};
constexpr int CB_LF[NCOMBO] = {0,1,2,1,0,1,2,1,2,3,2,1,2,3,0,1,2,3,4};
constexpr int CB_OFF[NCOMBO] = {0,1,10,35,44,53,80,125,170,245,350,375,420,495,600,625,700,825,1000};
constexpr int CB_SZ[NCOMBO]  = {1,9,25,9,9,27,45,45,75,105,25,45,75,105,25,75,125,175,225};
constexpr int C3TOT = 1225;

constexpr int C3OFFT[3][3][5] = {
  { {0,-1,-1,-1,-1}, {-1,1,-1,-1,-1}, {-1,-1,10,-1,-1} },
  { {-1,35,-1,-1,-1}, {44,53,80,-1,-1}, {-1,125,170,245,-1} },
  { {-1,-1,350,-1,-1}, {-1,375,420,495,-1}, {600,625,700,825,1000} }
};
constexpr int ROFFT[3][3] = {{0,64,128},{192,256,448},{640,704,896}};
constexpr int FOFFT[3]   = {0,8,32};

__device__ const double d_fact[11] = {1.,1.,2.,6.,24.,120.,720.,5040.,40320.,362880.,3628800.};

// ---------------------------------------------------------------------------
// Wigner 3j (complex basis, Racah) in double precision + real change of basis
// ---------------------------------------------------------------------------
__device__ double w3j_entry(int j1,int j2,int j3,int m1,int m2,int m3){
  if (m1+m2+m3 != 0) return 0.0;
  int dj = j1-j2; if (dj<0) dj=-dj;
  if (j3 < dj || j3 > j1+j2) return 0.0;
  int t1 = j2 - m1 - j3, t2 = j1 + m2 - j3;
  int kmin = 0; if (t1>kmin) kmin=t1; if (t2>kmin) kmin=t2;
  int kmax = j1+j2-j3; if (j1-m1<kmax) kmax=j1-m1; if (j2+m2<kmax) kmax=j2+m2;
  double s = 0.0;
  for (int k=kmin;k<=kmax;++k){
    double den = d_fact[k]*d_fact[k-t1]*d_fact[k-t2]*d_fact[j1+j2-j3-k]
               * d_fact[j1-m1-k]*d_fact[j2+m2-k];
    s += ((k&1)? -1.0:1.0)/den;
  }
  double pref = sqrt(d_fact[j1+j2-j3]*d_fact[j1-j2+j3]*d_fact[-j1+j2+j3]/d_fact[j1+j2+j3+1]
               * d_fact[j1+m1]*d_fact[j1-m1]*d_fact[j2+m2]*d_fact[j2-m2]
               * d_fact[j3+m3]*d_fact[j3-m3]);
  int ex = j1-j2-m3;
  if (ex & 1) pref = -pref;
  return pref*s;
}

__device__ void cob(int l, int r, int c, double& re, double& im){
  re = 0.0; im = 0.0;
  int mr = r - l, mc = c - l;
  const double s = 0.70710678118654752440;
  if (mr == 0) { if (mc == 0) re = 1.0; return; }
  if (mr > 0) {
    if (mc == mr)       re = (mr & 1) ? -s : s;
    else if (mc == -mr) re = s;
  } else {
    int m = -mr;
    if (mc == -m)      im = s;
    else if (mc == m)  im = (m & 1) ? s : -s;
  }
}

__global__ void c3_build_kernel(double* __restrict__ Tre, double* __restrict__ Tim){
  int idx = blockIdx.x*64 + threadIdx.x;
  if (idx >= C3TOT) return;
  int c = 0;
  while (c+1 < NCOMBO && idx >= CB_OFF[c+1]) ++c;
  int lo = CB_LO[c], li = CB_LI[c], lf = CB_LF[c];
  int n2 = 2*li+1, n3 = 2*lf+1;
  int loc = idx - CB_OFF[c];
  int a = loc/(n2*n3), b = (loc/n3)%n2, g = loc%n3;
  double sre=0.0, sim=0.0;
  for (int m1=-lo; m1<=lo; ++m1){
    for (int m2=-li; m2<=li; ++m2){
      int m3 = -m1-m2;
      if (m3 < -lf || m3 > lf) continue;
      double w = w3j_entry(lo,li,lf,m1,m2,m3);
      if (w == 0.0) continue;
      double r1,i1,r2,i2,r3,i3;
      cob(lo, a, m1+lo, r1,i1);
      cob(li, b, m2+li, r2,i2);
      cob(lf, g, m3+lf, r3,i3);
      double rr = r1*r2 - i1*i2, ri = r1*i2 + i1*r2;
      double fr = rr*r3 - ri*i3, fi = rr*i3 + ri*r3;
      sre += fr*w; sim += fi*w;
    }
  }
  Tre[idx] = sre; Tim[idx] = sim;
}

__global__ void c3_norm_kernel(const double* __restrict__ Tre, const double* __restrict__ Tim,
                               float* __restrict__ C3f){
  int c = blockIdx.x;
  int off = CB_OFF[c], sz = CB_SZ[c];
  int t = threadIdx.x;
  double sre=0.0, sim=0.0;
  for (int p=t; p<sz; p+=64){ double x=Tre[off+p], y=Tim[off+p]; sre+=x*x; sim+=y*y; }
  for (int m=1; m<64; m<<=1){ sre += __shfl_xor(sre, m, 64); sim += __shfl_xor(sim, m, 64); }
  bool useRe = (sre >= sim);
  double n = sqrt(useRe ? sre : sim);
  double inv = (n > 0.0) ? 1.0/n : 1.0;
  for (int p=t; p<sz; p+=64){
    double v = useRe ? Tre[off+p] : Tim[off+p];
    C3f[off+p] = (float)(v*inv);
  }
}

// ---------------------------------------------------------------------------
// W3t[c'][k], c' chunk-major: c' = chunk*64 + uv maps to original column
// ROFFT[lo][li] + uv*nlf + fi. 0.1 scale folded. Pitch 136, pad k>=100 = 0.
// ---------------------------------------------------------------------------
__global__ __launch_bounds__(256) void prep_w3t_kernel(const float* __restrict__ W3,
                                                       __hip_bfloat16* __restrict__ W3t){
  int idx = blockIdx.x*256 + threadIdx.x;
  if (idx >= 1216*136) return;
  int cp = idx/136, k = idx%136;
  int chunk = cp>>6, uv = cp&63;
  int lo = CB_LO[chunk], li = CB_LI[chunk], lf = CB_LF[chunk];
  int lmin = lo<li ? lo : li;
  int nlf = 2*lmin+1;
  int fi = lf - (lo>li ? lo-li : li-lo);
  int c = ROFFT[lo][li] + uv*nlf + fi;
  float v = (k < 100) ? 0.1f*W3[(size_t)k*NCOL + c] : 0.f;
  W3t[idx] = __float2bfloat16(v);
}

// ---------------------------------------------------------------------------
// Radial hidden chain -> h_bf[e][136] bf16 (pad zeroed)
// ---------------------------------------------------------------------------
__device__ __forceinline__ float swishf(float s){
  return SWISH_SCALE * s / (1.f + __expf(-s));
}

__global__ __launch_bounds__(256) void radial_hidden_kernel(
    const float* __restrict__ radii,
    const float* __restrict__ W0, const float* __restrict__ W1, const float* __restrict__ W2,
    __hip_bfloat16* __restrict__ h_bf, int E)
{
  __shared__ float sW[10000];
  __shared__ float sX[6400];   // [er][k], pitch 100
  __shared__ float sY[6400];
  __shared__ float sbas[640];
  const int t = threadIdx.x;
  const int et0 = blockIdx.x*64;

  for (int p=t; p<640; p+=256){
    int er = p/10, k = p%10;
    int eg = et0 + er;
    float r = (eg < E) ? radii[eg] : 0.f;
    float c = 0.7f + (2.5f/9.0f)*(float)k;
    float d = (r - c) * (9.0f/2.5f);
    sbas[p] = __expf(-d*d);
  }
  for (int p=t; p<1000; p+=256) sW[p] = W0[p]*0.3162277660168379f; // 1/sqrt(10)
  __syncthreads();
  for (int p=t; p<6400; p+=256){
    int er = p/100, o = p%100;
    float s = 0.f;
    #pragma unroll
    for (int k=0;k<10;++k) s += sbas[er*10+k]*sW[k*100+o];
    sX[p] = swishf(s);
  }
  __syncthreads();
  for (int p=t; p<10000; p+=256) sW[p] = W1[p]*0.1f;
  __syncthreads();
  for (int q=t; q<400; q+=256){
    int erb = (q/25)*4, ob = (q%25)*4;
    float acc[4][4] = {};
    for (int k=0;k<100;++k){
      float4 w = *(const float4*)&sW[k*100+ob];
      #pragma unroll
      for (int i=0;i<4;++i){
        float a = sX[(erb+i)*100+k];
        acc[i][0]+=a*w.x; acc[i][1]+=a*w.y; acc[i][2]+=a*w.z; acc[i][3]+=a*w.w;
      }
    }
    #pragma unroll
    for (int i=0;i<4;++i){
      float4 v = make_float4(swishf(acc[i][0]),swishf(acc[i][1]),swishf(acc[i][2]),swishf(acc[i][3]));
      *(float4*)&sY[(erb+i)*100+ob] = v;
    }
  }
  __syncthreads();
  for (int p=t; p<10000; p+=256) sW[p] = W2[p]*0.1f;
  __syncthreads();
  for (int q=t; q<400; q+=256){
    int erb = (q/25)*4, ob = (q%25)*4;
    float acc[4][4] = {};
    for (int k=0;k<100;++k){
      float4 w = *(const float4*)&sW[k*100+ob];
      #pragma unroll
      for (int i=0;i<4;++i){
        float a = sY[(erb+i)*100+k];
        acc[i][0]+=a*w.x; acc[i][1]+=a*w.y; acc[i][2]+=a*w.z; acc[i][3]+=a*w.w;
      }
    }
    #pragma unroll
    for (int i=0;i<4;++i){
      __hip_bfloat16 hv[4];
      #pragma unroll
      for (int j=0;j<4;++j) hv[j] = __float2bfloat16(swishf(acc[i][j]));
      *(short4*)&h_bf[(size_t)(et0+erb+i)*136 + ob] = *(short4*)hv;
    }
  }
  // zero the k=100..135 pad
  for (int p=t; p<64*36; p+=256){
    int er = p/36, k = 100 + p%36;
    h_bf[(size_t)(et0+er)*136 + k] = __float2bfloat16(0.f);
  }
}

// ---------------------------------------------------------------------------
// CSR of edges by target node
// ---------------------------------------------------------------------------
__global__ __launch_bounds__(256) void hist_kernel(const int* __restrict__ ei,
                                                   int* __restrict__ deg, int E){
  int e = blockIdx.x*256 + threadIdx.x;
  if (e < E) atomicAdd(&deg[ei[E+e]], 1);
}

__global__ __launch_bounds__(256) void scan_kernel(const int* __restrict__ deg,
                                                   int* __restrict__ off,
                                                   int* __restrict__ cursor, int N, int E){
  __shared__ int part[256], spref[256];
  const int t = threadIdx.x;
  const int CH = (N + 255)/256;
  int lo = t*CH, hi = lo+CH < N ? lo+CH : N;
  int s = 0;
  for (int n=lo; n<hi; ++n) s += deg[n];
  part[t] = s;
  __syncthreads();
  if (t == 0){
    int run = 0;
    for (int i=0;i<256;++i){ spref[i] = run; run += part[i]; }
  }
  __syncthreads();
  int run = spref[t];
  for (int n=lo; n<hi; ++n){ off[n] = run; cursor[n] = run; run += deg[n]; }
  if (t == 255) off[N] = E;
}

__global__ __launch_bounds__(256) void fill_kernel(const int* __restrict__ ei,
                                                   int* __restrict__ cursor,
                                                   int* __restrict__ eid, int E){
  int e = blockIdx.x*256 + threadIdx.x;
  if (e < E){
    int idx = atomicAdd(&cursor[ei[E+e]], 1);
    eid[idx] = e;
  }
}

// ---------------------------------------------------------------------------
// Gather: one 64-lane wave per node; writes every output element exactly once.
// ---------------------------------------------------------------------------
__global__ __launch_bounds__(64) void gather_kernel(const float* __restrict__ msg,
                                                    const int* __restrict__ off,
                                                    const int* __restrict__ eid,
                                                    float* __restrict__ out, int N){
  const int n = blockIdx.x;
  const int t = threadIdx.x;
  const int s = off[n], e1 = off[n+1];
  float a0 = 0.f, a1 = 0.f;
  for (int i=s; i<e1; ++i){
    const float* m = msg + (size_t)eid[i]*FEATD;
    a0 += m[t];
    if (t < 8) a1 += m[64+t];
  }
  out[(size_t)n*FEATD + t] = a0;
  if (t < 8) out[(size_t)n*FEATD + 64 + t] = a1;
}

// ---------------------------------------------------------------------------
// Fused GEMM+TP. 256 threads = 4 waves; 64 edges/block; 4 roles/edge.
// ---------------------------------------------------------------------------
template<int LO,int LI,int LF>
__device__ __forceinline__ void phase(
    int chunk, const __hip_bfloat16* __restrict__ W3t,
    __hip_bfloat16* sH, __hip_bfloat16* sW3, float* sRt,
    __hip_bfloat16* sF, float* sRsh, float* sKV, const float* sC3,
    float (&acc)[8][9], int t)
{
  constexpr int NO = 2*LO+1, NI = 2*LI+1, NF = 2*LF+1;
  constexpr int C3B = C3OFFT[LO][LI][LF];
  constexpr int FO  = FOFFT[LI];
  constexpr int AO  = (LO==0) ? 0 : (LO==1) ? 1 : 4;

  __syncthreads();   // [A] prev phase's consume done (sKV/sRt/sW3 free)

  // ---- stage this chunk's 64 W3t rows (17408 B) ----
  {
    const float4* g = (const float4*)(W3t + (size_t)chunk*64*136);
    float4* s = (float4*)sW3;
    for (int p=t; p<1088; p+=256) s[p] = g[p];
  }
  // ---- cooperative kv[e][o*NI+mi] = sum_mf C3 * y ----
  {
    const int le = t & 63, wv = t >> 6;
    float y[NF];
    #pragma unroll
    for (int mf=0; mf<NF; ++mf) y[mf] = sRsh[le*26 + LF*LF + mf];
    for (int it = wv; it < NO*NI; it += 4){
      float s = 0.f;
      #pragma unroll
      for (int mf=0; mf<NF; ++mf) s += sC3[C3B + it*NF + mf] * y[mf];
      sKV[le*26 + it] = s;
    }
  }
  __syncthreads();   // [B] sW3 + sKV visible

  // ---- MFMA: Rt_chunk[c=uv][e], 64x64, K=128; each wave does 16 edges ----
  {
    const int lane = t & 63, wv = t >> 6;
    const int lr = lane & 15, lq = lane >> 4;
    f32x4 a4[4] = {};
    #pragma unroll
    for (int ks=0; ks<4; ++ks){
      bf16x8 b = *(const bf16x8*)&sH[(wv*16+lr)*136 + ks*32 + lq*8];
      #pragma unroll
      for (int ct=0; ct<4; ++ct){
        bf16x8 a = *(const bf16x8*)&sW3[(ct*16+lr)*136 + ks*32 + lq*8];
        a4[ct] = __builtin_amdgcn_mfma_f32_16x16x32_bf16(a, b, a4[ct], 0, 0, 0);
      }
    }
    #pragma unroll
    for (int ct=0; ct<4; ++ct)
      #pragma unroll
      for (int r=0; r<4; ++r)
        sRt[(ct*16 + lq*4 + r)*66 + wv*16 + lr] = a4[ct][r];
  }
  __syncthreads();   // [C] sRt visible

  // ---- TP consume: 4 roles/edge, role handles v in {2*role, 2*role+1} ----
  {
    const int e = t >> 2, role = t & 3;
    float Fv[2][NI];
    #pragma unroll
    for (int vv=0; vv<2; ++vv)
      #pragma unroll
      for (int mi=0; mi<NI; ++mi)
        Fv[vv][mi] = __bfloat162float(sF[e*74 + FO + (role*2+vv)*NI + mi]);
    float tmp[2][NO];
    #pragma unroll
    for (int vv=0; vv<2; ++vv)
      #pragma unroll
      for (int o=0; o<NO; ++o) tmp[vv][o] = 0.f;
    #pragma unroll
    for (int o=0; o<NO; ++o)
      #pragma unroll
      for (int mi=0; mi<NI; ++mi){
        float kvv = sKV[e*26 + o*NI + mi];
        #pragma unroll
        for (int vv=0; vv<2; ++vv) tmp[vv][o] += kvv * Fv[vv][mi];
      }
    #pragma unroll
    for (int u=0; u<8; ++u)
      #pragma unroll
      for (int vv=0; vv<2; ++vv){
        float r = sRt[(u*8 + role*2 + vv)*66 + e];
        #pragma unroll
        for (int o=0; o<NO; ++o) acc[u][AO+o] += r * tmp[vv][o];
      }
  }
}

__global__ __launch_bounds__(256,2) void fused_kernel(
    const float* __restrict__ feats, const int* __restrict__ ei,
    const float* __restrict__ rsh, const __hip_bfloat16* __restrict__ h_bf,
    const __hip_bfloat16* __restrict__ W3t, const float* __restrict__ C3g,
    float* __restrict__ msg, int E)
{
  __shared__ __align__(16) __hip_bfloat16 sH[64*136];
  __shared__ __align__(16) __hip_bfloat16 sW3[64*136];
  __shared__ float sRt[64*66];
  __shared__ __hip_bfloat16 sF[64*74];
  __shared__ float sRsh[64*26];
  __shared__ float sKV[64*26];
  __shared__ float sC3[1228];
  __shared__ int sSrc[64];

  const int t = threadIdx.x;
  const int eb = blockIdx.x*64;

  // ---- prologue staging ----
  {
    const float4* g = (const float4*)(h_bf + (size_t)eb*136);
    float4* s = (float4*)sH;
    for (int p=t; p<1088; p+=256) s[p] = g[p];
  }
  for (int p=t; p<64; p+=256){
    int e = eb + p;
    sSrc[p] = (e < E) ? ei[e] : 0;
  }
  for (int p=t; p<1600; p+=256){
    int el = p/25, j = p%25;
    int e = eb + el;
    sRsh[el*26 + j] = (e < E) ? rsh[(size_t)e*25 + j] : 0.f;
  }
  for (int p=t; p<C3TOT; p+=256) sC3[p] = C3g[p];
  __syncthreads();
  for (int p=t; p<64*72; p+=256){
    int el = p/72, j = p%72;
    sF[el*74 + j] = __float2bfloat16(feats[(size_t)sSrc[el]*72 + j]);
  }

  float acc[8][9];
  #pragma unroll
  for (int u=0; u<8; ++u)
    #pragma unroll
    for (int j=0; j<9; ++j) acc[u][j] = 0.f;

  // ---- 19 phases (chunk order = CB tables) ----
  phase<0,0,0>( 0, W3t, sH, sW3, sRt, sF, sRsh, sKV, sC3, acc, t);
  phase<0,1,1>( 1, W3t, sH, sW3, sRt, sF, sRsh, sKV, sC3, acc, t);
  phase<0,2,2>( 2, W3t, sH, sW3, sRt, sF, sRsh, sKV, sC3, acc, t);
  phase<1,0,1>( 3, W3t, sH, sW3, sRt, sF, sRsh, sKV, sC3, acc, t);
  phase<1,1,0>( 4, W3t, sH, sW3, sRt, sF, sRsh, sKV, sC3, acc, t);
  phase<1,1,1>( 5, W3t, sH, sW3, sRt, sF, sRsh, sKV, sC3, acc, t);
  phase<1,1,2>( 6, W3t, sH, sW3, sRt, sF, sRsh, sKV, sC3, acc, t);
  phase<1,2,1>( 7, W3t, sH, sW3, sRt, sF, sRsh, sKV, sC3, acc, t);
  phase<1,2,2>( 8, W3t, sH, sW3, sRt, sF, sRsh, sKV, sC3, acc, t);
  phase<1,2,3>( 9, W3t, sH, sW3, sRt, sF, sRsh, sKV, sC3, acc, t);
  phase<2,0,2>(10, W3t, sH, sW3, sRt, sF, sRsh, sKV, sC3, acc, t);
  phase<2,1,1>(11, W3t, sH, sW3, sRt, sF, sRsh, sKV, sC3, acc, t);
  phase<2,1,2>(12, W3t, sH, sW3, sRt, sF, sRsh, sKV, sC3, acc, t);
  phase<2,1,3>(13, W3t, sH, sW3, sRt, sF, sRsh, sKV, sC3, acc, t);
  phase<2,2,0>(14, W3t, sH, sW3, sRt, sF, sRsh, sKV, sC3, acc, t);
  phase<2,2,1>(15, W3t, sH, sW3, sRt, sF, sRsh, sKV, sC3, acc, t);
  phase<2,2,2>(16, W3t, sH, sW3, sRt, sF, sRsh, sKV, sC3, acc, t);
  phase<2,2,3>(17, W3t, sH, sW3, sRt, sF, sRsh, sKV, sC3, acc, t);
  phase<2,2,4>(18, W3t, sH, sW3, sRt, sF, sRsh, sKV, sC3, acc, t);

  // ---- quad merge (lanes 4k..4k+3 share an edge) + dense message write ----
  #pragma unroll
  for (int u=0; u<8; ++u)
    #pragma unroll
    for (int j=0; j<9; ++j){
      acc[u][j] += __shfl_xor(acc[u][j], 1, 64);
      acc[u][j] += __shfl_xor(acc[u][j], 2, 64);
    }

  const int e = t >> 2, role = t & 3;
  const int eg = eb + e;
  if (eg < E){
    float* dst = msg + (size_t)eg*FEATD;
    #pragma unroll
    for (int du=0; du<2; ++du){
      int u = role*2 + du;
      dst[u] = acc[u][0]*0.72360125f;                       // lo=0: sqrt(pi/6)
      #pragma unroll
      for (int o=0; o<3; ++o)
        dst[8 + u*3 + o] = acc[u][1+o]*0.8204867f;          // lo=1: sqrt(3pi/14)
      #pragma unroll
      for (int o=0; o<5; ++o)
        dst[32 + u*5 + o] = acc[u][4+o]*0.9341652f;         // lo=2: sqrt(5pi/18)
    }
  }
}

// ---------------------------------------------------------------------------
extern "C" void kernel_launch(void* const* d_in, const int* in_sizes, int n_in,
                              void* d_out, int out_size, void* d_ws, size_t ws_size,
                              hipStream_t stream)
{
  const float* feats = (const float*)d_in[0];
  const int*   ei    = (const int*)d_in[1];
  const float* radii = (const float*)d_in[2];
  const float* rsh   = (const float*)d_in[3];
  const float* W0    = (const float*)d_in[4];
  const float* W1    = (const float*)d_in[5];
  const float* W2    = (const float*)d_in[6];
  const float* W3    = (const float*)d_in[7];
  float* out = (float*)d_out;
  const int E = in_sizes[2];
  const int N = in_sizes[0]/FEATD;

  const int EPAD = ((E + 63)/64)*64;
  const int NBLK = EPAD/64;

  char* ws = (char*)d_ws;
  size_t off_b = 0;
  float*  C3f = (float*)(ws + off_b);  off_b += 8192;
  double* Tre = (double*)(ws + off_b); off_b += 12288;
  double* Tim = (double*)(ws + off_b); off_b += 12288;          // 32768
  __hip_bfloat16* W3t  = (__hip_bfloat16*)(ws + off_b); off_b += 335872;  // 368640
  __hip_bfloat16* h_bf = (__hip_bfloat16*)(ws + off_b); off_b += (size_t)EPAD*272;
  float* msg = (float*)(ws + off_b);   off_b += (size_t)EPAD*FEATD*4;
  int* deg    = (int*)(ws + off_b);    off_b += (size_t)N*4;
  int* offv   = (int*)(ws + off_b);    off_b += (size_t)(N+1)*4;
  int* cursor = (int*)(ws + off_b);    off_b += (size_t)N*4;
  int* eid    = (int*)(ws + off_b);    off_b += (size_t)E*4;

  // constants / tables
  c3_build_kernel<<<dim3((C3TOT+63)/64), dim3(64), 0, stream>>>(Tre, Tim);
  c3_norm_kernel<<<dim3(NCOMBO), dim3(64), 0, stream>>>(Tre, Tim, C3f);
  prep_w3t_kernel<<<dim3((1216*136+255)/256), dim3(256), 0, stream>>>(W3, W3t);

  // CSR of edges by target
  hipMemsetAsync(deg, 0, (size_t)N*4, stream);
  hist_kernel<<<dim3((E+255)/256), dim3(256), 0, stream>>>(ei, deg, E);
  scan_kernel<<<dim3(1), dim3(256), 0, stream>>>(deg, offv, cursor, N, E);
  fill_kernel<<<dim3((E+255)/256), dim3(256), 0, stream>>>(ei, cursor, eid, E);

  // main pipeline
  radial_hidden_kernel<<<dim3(NBLK), dim3(256), 0, stream>>>(radii, W0, W1, W2, h_bf, E);
  fused_kernel<<<dim3(NBLK), dim3(256), 0, stream>>>(feats, ei, rsh, h_bf, W3t, C3f, msg, E);
  gather_kernel<<<dim3(N), dim3(64), 0, stream>>>(msg, offv, eid, out, N);
}